// Round 5
// baseline (1348.553 us; speedup 1.0000x reference)
//
#include <hip/hip_runtime.h>
#include <hip/hip_bf16.h>
#include <cstdint>

// SimplifiedMambaSSM on MI355X (gfx950)
// B=8, T=4096, D_MODEL=1024, D_STATE=16. Rows M = B*T = 32768.
//
// Pipeline (R5: K3/K4 folded into the fused kernel as a chunk-pipelined
// produce phase -- they were ~150us of latency-bound standalone dispatches
// whose work is row-local and fits under the scan's 3.35us/chunk shadow):
//  K1 convert : x, W_gate, [W_delta;W_B;W_C] -> bf16 copies; zeroes sync[].
//  K2 gemm    : G = Xb @ Wgb^T  (bf16 MFMA, 128x128 tiles, XCD-swizzled).
//  K5 fused   : blocks 0..7   = scan (one per batch, wave-specialized,
//                               consumer wave at setprio(3));
//               blocks 8..519 = workers, 3 roles chunk-pipelined:
//                 produce(k): LN+gate+proj for its 2 rows of chunk k
//                   (waves 0-3 row of b0, 4-7 row of b1; full row per wave,
//                   16 cols/lane; butterfly LN; xg in f32; 12 VALU dots vs
//                   Wcat; softplus/exp epilogue -> {u,v} agent write-through
//                   to UV; Ct -> LDS ring). Publish rdy[b][k] (atomicAdd
//                   after __syncthreads' vmcnt drain; target 128).
//                 out(c): y = (Ct.*h)@W_out^T + D.*x for the same 2 rows,
//                   gated on scan flags; Ct from LDS ring; hs agent loads.
//               Scan producer waves gate UV staging on rdy[b][c+1]
//               (bounded spin) and load UV with agent-scope loads.
//   Deadlock-freedom: 520 blocks <= 768 co-resident (50KB LDS, LB(512,6)
//   => 3 blocks/CU). produce waits on nothing (LOOKAHEAD=4 ahead of out);
//   scan waits only on rdy; out waits only on scan flags. Acyclic. ALL
//   spins bounded (~0.2s) => any protocol bug = absmax failure, not hang.
//
#define M_TOK   32768
#define LNEPS   1e-5f
#define TWO_LOG2E 2.8853900817779268f   // 2/ln(2)

typedef float  f32x4 __attribute__((ext_vector_type(4)));
typedef short  s16x8 __attribute__((ext_vector_type(8)));
typedef unsigned long long ull;

__device__ __forceinline__ unsigned short f2b(float v) {
  return __builtin_bit_cast(unsigned short, __float2bfloat16(v));
}
__device__ __forceinline__ float b2f(unsigned short u) {
  return __bfloat162float(__builtin_bit_cast(__hip_bfloat16, u));
}

// async global->LDS, 16B per lane. LDS dest is wave-uniform base + lane*16.
__device__ __forceinline__ void async_cp16(const void* g, void* l) {
  using gp = const __attribute__((address_space(1))) char*;
  using lp = __attribute__((address_space(3))) char*;
  __builtin_amdgcn_global_load_lds((gp)(uint64_t)g,
                                   (lp)(uint32_t)(uint64_t)l, 16, 0, 0);
}

// ---------------------------------------------------------------- K1 convert
__global__ __launch_bounds__(256) void k_convert(
    const float* __restrict__ x, const float* __restrict__ wg,
    const float* __restrict__ wd, const float* __restrict__ wb,
    const float* __restrict__ wc,
    unsigned short* __restrict__ Xb, unsigned short* __restrict__ Wgb,
    unsigned short* __restrict__ Wcat, int* __restrict__ sync_arr) {
  int i = blockIdx.x * 256 + threadIdx.x;   // one float4 per thread
  if (blockIdx.x == 0) {                    // zero flags[8] + rdy[256]
    __hip_atomic_store(&sync_arr[threadIdx.x], 0, __ATOMIC_RELAXED,
                       __HIP_MEMORY_SCOPE_AGENT);
    if (threadIdx.x < 8)
      __hip_atomic_store(&sync_arr[256 + threadIdx.x], 0, __ATOMIC_RELAXED,
                         __HIP_MEMORY_SCOPE_AGENT);
  }
  const float* src;
  unsigned short* dst;
  if (i < 8388608) {                  // x: 33554432 floats
    src = x + (size_t)i * 4; dst = Xb + (size_t)i * 4;
  } else if (i < 8650752) {           // W_gate: 1048576 floats
    int j = i - 8388608;
    src = wg + (size_t)j * 4; dst = Wgb + (size_t)j * 4;
  } else {                            // Wcat = [W_delta; W_B; W_C], 49152 floats
    int j = i - 8650752;
    int e = j * 4;
    if (e < 16384)       src = wd + e;
    else if (e < 32768)  src = wb + (e - 16384);
    else                 src = wc + (e - 32768);
    dst = Wcat + e;
  }
  float4 v = *(const float4*)src;
  ushort4 o;
  o.x = f2b(v.x); o.y = f2b(v.y); o.z = f2b(v.z); o.w = f2b(v.w);
  *(ushort4*)dst = o;
}

// ------------------------------------------------------------- K2 gate GEMM
// G[m][n] = sum_k Xb[m][k] * Wgb[n][k]   (NT, both K-contiguous)
// 128x128 block tile, 4 waves in 2x2, each wave 64x64 = 4x4 MFMA 16x16x32.
__global__ __launch_bounds__(256, 2) void k_gemm_gate(
    const unsigned short* __restrict__ A,   // [32768][1024] bf16
    const unsigned short* __restrict__ Bm,  // [1024][1024] bf16 (W_gate rows)
    unsigned short* __restrict__ C) {       // [32768][1024] bf16
  __shared__ unsigned short As[128 * 32];   // 8 KB
  __shared__ unsigned short Bs[128 * 32];   // 8 KB
  const int tid  = threadIdx.x;
  const int wave = tid >> 6, lane = tid & 63;
  const int wr = wave >> 1, wc = wave & 1;
  const int lrow = lane & 15, lq = lane >> 4;
  // XCD-aware swizzle: each XCD owns 32 M-panels x all 8 N-tiles.
  const int lin  = blockIdx.y * gridDim.x + blockIdx.x;     // 0..2047
  const int unit = (lin & 7) * 256 + (lin >> 3);
  const int m0 = (unit >> 3) * 128;
  const int n0 = (unit & 7) * 128;
  const int crow  = tid >> 2;               // staging chunk row (rep 0)
  const int ccol  = (tid & 3) * 8;          // staging chunk col (elems)

  f32x4 acc[4][4];
#pragma unroll
  for (int i = 0; i < 4; i++)
#pragma unroll
    for (int j = 0; j < 4; j++) acc[i][j] = (f32x4){0.f, 0.f, 0.f, 0.f};

  for (int k0 = 0; k0 < 1024; k0 += 32) {
    async_cp16(A + (size_t)(m0 + crow) * 1024 + k0 + ccol,
               (void*)(As + (wave * 64) * 8));
    async_cp16(A + (size_t)(m0 + crow + 64) * 1024 + k0 + ccol,
               (void*)(As + (256 + wave * 64) * 8));
    async_cp16(Bm + (size_t)(n0 + crow) * 1024 + k0 + ccol,
               (void*)(Bs + (wave * 64) * 8));
    async_cp16(Bm + (size_t)(n0 + crow + 64) * 1024 + k0 + ccol,
               (void*)(Bs + (256 + wave * 64) * 8));
    __syncthreads();   // drains vmcnt (global_load_lds) before LDS reads

    s16x8 af[4], bfr[4];
#pragma unroll
    for (int i = 0; i < 4; i++)
      af[i] = *(const s16x8*)(As + (wr * 64 + i * 16 + lrow) * 32 + lq * 8);
#pragma unroll
    for (int j = 0; j < 4; j++)
      bfr[j] = *(const s16x8*)(Bs + (wc * 64 + j * 16 + lrow) * 32 + lq * 8);
#pragma unroll
    for (int i = 0; i < 4; i++)
#pragma unroll
      for (int j = 0; j < 4; j++)
        acc[i][j] = __builtin_amdgcn_mfma_f32_16x16x32_bf16(
            af[i], bfr[j], acc[i][j], 0, 0, 0);
    __syncthreads();
  }

  // C/D layout: col = lane&15, row = (lane>>4)*4 + reg
#pragma unroll
  for (int i = 0; i < 4; i++)
#pragma unroll
    for (int j = 0; j < 4; j++)
#pragma unroll
      for (int r = 0; r < 4; r++) {
        int row = m0 + wr * 64 + i * 16 + lq * 4 + r;
        int col = n0 + wc * 64 + j * 16 + lrow;
        C[(size_t)row * 1024 + col] = f2b(acc[i][j][r]);
      }
}

// --------------------------------------------------- K5 fused scan/proj/out
#define TC 128                // steps per chunk
#define NCH (4096 / TC)       // 32 chunks
#define NWRK 512              // worker blocks; grid = 8 + 512 = 520 <= 768
#define LOOKA 4               // produce lookahead (chunks)

__device__ __forceinline__ void load16(float2 (&P)[16], const float* uvb,
                                       int j, int lane) {
#pragma unroll
  for (int i = 0; i < 16; ++i)
    P[i] = *(const float2*)(uvb + ((j * 16 + i) * 16 + lane) * 2);
}
__device__ __forceinline__ void fast16(float2 (&P)[16], float& r, float& h,
                                       float* hhb, int j, int lane) {
#pragma unroll
  for (int i = 0; i < 16; ++i) {
    float w = fmaf(P[i].y, r, P[i].x);
    float e = __builtin_amdgcn_exp2f(w);
    r = __builtin_amdgcn_rcpf(e + 1.0f);
    h = fmaf(-2.0f, r, 1.0f);
    hhb[(j * 16 + i) * 16 + lane] = h;
  }
}
__device__ __forceinline__ void slow16(float2 (&P)[16], float& h,
                                       const float* mb, float* hhb,
                                       int j, int lane) {
#pragma unroll
  for (int i = 0; i < 16; ++i) {
    float v  = P[i].y, u = P[i].x;
    float A2 = -0.5f * v;
    float B2 = fmaf(0.5f, v, u);
    float w  = fmaf(A2, h, B2);
    float e  = __builtin_amdgcn_exp2f(w);
    float rr = __builtin_amdgcn_rcpf(e + 1.0f);
    float th = fmaf(-2.0f, rr, 1.0f);
    float m  = mb[j * 16 + i];
    h = fmaf(m, th - h, h);
    hhb[(j * 16 + i) * 16 + lane] = h;
  }
}
__device__ __forceinline__ float red64(float v) {
#pragma unroll
  for (int off = 32; off >= 1; off >>= 1) v += __shfl_xor(v, off, 64);
  return v;
}

__global__ __launch_bounds__(512, 6) void k_fused(
    float* __restrict__ UV, const float* __restrict__ mask,
    const float* __restrict__ h0, float* __restrict__ hs,
    float* __restrict__ hfin,
    const float* __restrict__ x,
    const float* __restrict__ Wout, const float* __restrict__ Dd,
    float* __restrict__ y, int* __restrict__ sync_arr,
    const unsigned short* __restrict__ Gb, const float* __restrict__ bg,
    const float* __restrict__ lnw, const float* __restrict__ lnb,
    const unsigned short* __restrict__ Wcat, const float* __restrict__ A_diag) {
  __shared__ float uvL[2][TC * 32];    // 32 KB (scan role)
  __shared__ float hhL[2][TC * 16];    // 16 KB (scan role)
  __shared__ float mskL[2][TC];        // 1 KB  (scan role)
  __shared__ float ctL[8][2][16];      // 4 KB  (worker Ct ring, LOOKA<8)

  const int tid = threadIdx.x;
  int* flags = sync_arr;        // [8]
  int* rdy   = sync_arr + 8;    // [8][32]

  if (blockIdx.x >= 8) {
    // ============================ WORKER ROLE ============================
    const int o    = blockIdx.x - 8;          // 0..511
    const int wv   = tid >> 6;
    const int lane = tid & 63;
    const int b0   = o >> 7;                  // 0..3
    const int b1   = b0 + 4;                  // 4..7
    const int j0   = o & 127;
    const int prow = wv >> 2;                 // 0 -> row of b0, 1 -> row of b1
    const int wir  = wv & 3;                  // wave-in-row
    const int c16  = lane * 16;               // col base (full row per wave)
    const int bb   = prow ? b1 : b0;

    // ---- per-lane constant vectors for produce (L1-hot after chunk 0)
    float bgv[16], lwv[16], lbv[16], adv[4];
#pragma unroll
    for (int q = 0; q < 4; q++) {
      *(float4*)&bgv[q * 4] = *(const float4*)(bg  + c16 + q * 4);
      *(float4*)&lwv[q * 4] = *(const float4*)(lnw + c16 + q * 4);
      *(float4*)&lbv[q * 4] = *(const float4*)(lnb + c16 + q * 4);
      adv[q] = A_diag[wir + 4 * q];
    }
    // ---- out-role constants
    const int d0 = wv * 128 + lane * 2;
    float wa[16], wbv[16];
#pragma unroll
    for (int q = 0; q < 4; q++) {
      *(float4*)&wa[q * 4]  = *(const float4*)(Wout + (size_t)d0 * 16 + q * 4);
      *(float4*)&wbv[q * 4] = *(const float4*)(Wout + (size_t)(d0 + 1) * 16 + q * 4);
    }
    float2 D2 = *(const float2*)(Dd + d0);

    for (int c = -LOOKA; c < NCH; ++c) {
      const int kp = c + LOOKA;
      if (kp < NCH) {
        // -------------------- produce(kp): LN + gate + proj for my row
        const size_t grow = (size_t)bb * 4096 + (size_t)kp * TC + j0;
        const unsigned short* gp = Gb + grow * 1024 + c16;
        s16x8 gA = *(const s16x8*)gp;
        s16x8 gB = *(const s16x8*)(gp + 8);
        float v[16];
#pragma unroll
        for (int i = 0; i < 8; i++) {
          v[i]     = b2f((unsigned short)gA[i]) + bgv[i];
          v[8 + i] = b2f((unsigned short)gB[i]) + bgv[8 + i];
        }
        float s = 0.f, ss = 0.f;
#pragma unroll
        for (int i = 0; i < 16; i++) { s += v[i]; ss += v[i] * v[i]; }
        s = red64(s); ss = red64(ss);
        float mu  = s * (1.0f / 1024.0f);
        float var = ss * (1.0f / 1024.0f) - mu * mu;
        float rs  = rsqrtf(var + LNEPS);
        float xg[16];
#pragma unroll
        for (int q = 0; q < 4; q++) {
          float4 x4 = *(const float4*)(x + grow * 1024 + c16 + q * 4);
          float xv4[4] = {x4.x, x4.y, x4.z, x4.w};
#pragma unroll
          for (int i2 = 0; i2 < 4; i2++) {
            int i = q * 4 + i2;
            float u = (v[i] - mu) * rs * lwv[i] + lbv[i];
            float g = 1.0f / (1.0f + __expf(-u));
            xg[i] = g * xv4[i2];
          }
        }
        // 12 dots vs Wcat (delta s0, B s0+16, C s0+32) for s0 = wir+4k
#pragma unroll
        for (int k4 = 0; k4 < 4; k4++) {
          const int s0 = wir + 4 * k4;
          const unsigned short* wd = Wcat + (size_t)s0 * 1024 + c16;
          float zD = 0.f, zB = 0.f, zC = 0.f;
          {
            s16x8 a0 = *(const s16x8*)wd;
            s16x8 a1 = *(const s16x8*)(wd + 8);
            s16x8 b0v = *(const s16x8*)(wd + 16 * 1024);
            s16x8 b1v = *(const s16x8*)(wd + 16 * 1024 + 8);
            s16x8 c0v = *(const s16x8*)(wd + 32 * 1024);
            s16x8 c1v = *(const s16x8*)(wd + 32 * 1024 + 8);
#pragma unroll
            for (int i = 0; i < 8; i++) {
              zD = fmaf(xg[i],     b2f((unsigned short)a0[i]), zD);
              zD = fmaf(xg[8 + i], b2f((unsigned short)a1[i]), zD);
              zB = fmaf(xg[i],     b2f((unsigned short)b0v[i]), zB);
              zB = fmaf(xg[8 + i], b2f((unsigned short)b1v[i]), zB);
              zC = fmaf(xg[i],     b2f((unsigned short)c0v[i]), zC);
              zC = fmaf(xg[8 + i], b2f((unsigned short)c1v[i]), zC);
            }
          }
          zD = red64(zD); zB = red64(zB); zC = red64(zC);
          float sp = fmaxf(zD, 0.0f) + log1pf(__expf(-fabsf(zD)));
          float A2 = __expf(sp * adv[k4]) * TWO_LOG2E;
          float B2 = zB * TWO_LOG2E;
          if (lane == 0) {
            float2 uvv; uvv.x = A2 + B2; uvv.y = -2.0f * A2;
            __hip_atomic_store((ull*)(UV + grow * 32 + s0 * 2),
                               __builtin_bit_cast(ull, uvv),
                               __ATOMIC_RELAXED, __HIP_MEMORY_SCOPE_AGENT);
            ctL[kp & 7][prow][s0] = zC;
          }
        }
        __syncthreads();                 // drains all waves' UV stores
        if (tid == 0) {
          atomicAdd(&rdy[b0 * 32 + kp], 1);
          atomicAdd(&rdy[b1 * 32 + kp], 1);
        }
      }
      if (c < 0) continue;
      // ------------------------ out(c): gated on scan flags
      size_t r0 = (size_t)b0 * 4096 + (size_t)c * TC + j0;
      size_t r1 = (size_t)b1 * 4096 + (size_t)c * TC + j0;
      int spins = 0;
      for (;;) {
        int f = 0;
        if (lane == 0) {
          int fa = __hip_atomic_load(&flags[b0], __ATOMIC_RELAXED,
                                     __HIP_MEMORY_SCOPE_AGENT);
          int fb = __hip_atomic_load(&flags[b1], __ATOMIC_RELAXED,
                                     __HIP_MEMORY_SCOPE_AGENT);
          f = (fa < fb) ? fa : fb;
        }
        f = __shfl(f, 0);
        if (f > c || spins > (1 << 18)) break;
        ++spins;
        __builtin_amdgcn_s_sleep(32);
      }
      float cv0 = ctL[c & 7][0][lane & 15];
      float cv1 = ctL[c & 7][1][lane & 15];
      float hv0 = __hip_atomic_load(&hs[r0 * 16 + (lane & 15)],
                                    __ATOMIC_RELAXED, __HIP_MEMORY_SCOPE_AGENT);
      float hv1 = __hip_atomic_load(&hs[r1 * 16 + (lane & 15)],
                                    __ATOMIC_RELAXED, __HIP_MEMORY_SCOPE_AGENT);
      float2 x20 = *(const float2*)(x + r0 * 1024 + d0);
      float2 x21 = *(const float2*)(x + r1 * 1024 + d0);
      float sv0 = cv0 * hv0;
      float sv1 = cv1 * hv1;
      float a0x = D2.x * x20.x, a0y = D2.y * x20.y;
      float a1x = D2.x * x21.x, a1y = D2.y * x21.y;
#pragma unroll
      for (int sq = 0; sq < 16; sq++) {
        float s0v = __shfl(sv0, sq);
        float s1v = __shfl(sv1, sq);
        a0x = fmaf(wa[sq], s0v, a0x);
        a0y = fmaf(wbv[sq], s0v, a0y);
        a1x = fmaf(wa[sq], s1v, a1x);
        a1y = fmaf(wbv[sq], s1v, a1y);
      }
      float2 o0; o0.x = a0x; o0.y = a0y;
      float2 o1; o1.x = a1x; o1.y = a1y;
      *(float2*)(y + r0 * 1024 + d0) = o0;
      *(float2*)(y + r1 * 1024 + d0) = o1;
    }
    return;
  }

  // ============================== SCAN ROLE ==============================
  const int b   = blockIdx.x;
  const float* pm = mask + (size_t)b * 4096;
  const size_t uvbase = (size_t)b * 4096 * 32;   // floats
  const size_t hsbase = (size_t)b * 4096 * 16;   // floats

  if (tid < 64) __builtin_amdgcn_s_setprio(3);   // critical recurrence wave

  float h = 0.f, r = 0.f;
  if (tid < 16) {
    h = h0[b * 16 + tid];
    r = 0.5f - 0.5f * h;        // invariant r = (1-h)/2
  }

  // ---- priming: stage chunk 0 (gated on rdy[b][0])
  if (tid >= 64) {
    int spins = 0;
    for (;;) {
      int f = 0;
      if ((tid & 63) == 0)
        f = __hip_atomic_load(&rdy[b * 32 + 0], __ATOMIC_RELAXED,
                              __HIP_MEMORY_SCOPE_AGENT);
      f = __shfl(f, 0);
      if (f >= 128 || spins > (1 << 18)) break;
      ++spins;
      __builtin_amdgcn_s_sleep(16);
    }
    int pt = tid - 64;                          // 0..447
    const ull* src = (const ull*)(UV + uvbase);
    ull* dst = (ull*)uvL[0];
    for (int i = pt; i < TC * 16; i += 448)
      dst[i] = __hip_atomic_load(&src[i], __ATOMIC_RELAXED,
                                 __HIP_MEMORY_SCOPE_AGENT);
    if (tid < 128) {
      int l = tid - 64;
      mskL[0][l]      = pm[l];
      mskL[0][l + 64] = pm[l + 64];
    }
  }
  __syncthreads();

  for (int c = 0; c < NCH; ++c) {
    // publish chunks 0..c-2 (flushed in iter c-1; barrier drained vmcnt)
    if (c >= 2 && tid == 511) {
      __hip_atomic_store(&flags[b], c - 1, __ATOMIC_RELAXED,
                         __HIP_MEMORY_SCOPE_AGENT);
    }
    const int p = c & 1;
    if (tid < 64) {
      // ---------------- consumer wave
      const int lane = tid;
      float mv0 = mskL[p][2 * lane], mv1 = mskL[p][2 * lane + 1];
      bool on = (mv0 == 1.0f) && (mv1 == 1.0f);
      bool allones = (__ballot(on) == 0xFFFFFFFFFFFFFFFFull);
      if (lane < 16) {
        const float* uvb = uvL[p];
        float* hhb = hhL[p];
        float2 Pa[16], Pb[16];
        load16(Pa, uvb, 0, lane);
        if (allones) {
#pragma unroll
          for (int j = 0; j < 8; j += 2) {
            load16(Pb, uvb, j + 1, lane);
            fast16(Pa, r, h, hhb, j, lane);
            if (j + 2 < 8) load16(Pa, uvb, j + 2, lane);
            fast16(Pb, r, h, hhb, j + 1, lane);
          }
        } else {
#pragma unroll
          for (int j = 0; j < 8; j += 2) {
            load16(Pb, uvb, j + 1, lane);
            slow16(Pa, h, mskL[p], hhb, j, lane);
            if (j + 2 < 8) load16(Pa, uvb, j + 2, lane);
            slow16(Pb, h, mskL[p], hhb, j + 1, lane);
          }
          r = 0.5f - 0.5f * h;
        }
      }
    } else {
      // ---------------- producer waves 1..7
      int pt = tid - 64;                        // 0..447
      if (c + 1 < NCH) {
        int spins = 0;
        for (;;) {
          int f = 0;
          if ((tid & 63) == 0)
            f = __hip_atomic_load(&rdy[b * 32 + c + 1], __ATOMIC_RELAXED,
                                  __HIP_MEMORY_SCOPE_AGENT);
          f = __shfl(f, 0);
          if (f >= 128 || spins > (1 << 18)) break;
          ++spins;
          __builtin_amdgcn_s_sleep(16);
        }
        const ull* src = (const ull*)(UV + uvbase + (size_t)(c + 1) * TC * 32);
        ull* dst = (ull*)uvL[(c + 1) & 1];
        for (int i = pt; i < TC * 16; i += 448)
          dst[i] = __hip_atomic_load(&src[i], __ATOMIC_RELAXED,
                                     __HIP_MEMORY_SCOPE_AGENT);
        if (tid < 128) {
          int l = tid - 64;
          mskL[(c + 1) & 1][l]      = pm[(c + 1) * TC + l];
          mskL[(c + 1) & 1][l + 64] = pm[(c + 1) * TC + l + 64];
        }
      }
      if (c > 0) {
        // flush chunk c-1 h-history: agent write-through 8B stores
        const ull* s2 = (const ull*)hhL[(c - 1) & 1];
        ull* d2 = (ull*)(hs + hsbase + (size_t)(c - 1) * TC * 16);
        for (int i = pt; i < TC * 8; i += 448)
          __hip_atomic_store(&d2[i], s2[i], __ATOMIC_RELAXED,
                             __HIP_MEMORY_SCOPE_AGENT);
      }
    }
    __syncthreads();
  }

  // ---- epilogue: store last chunk's h-history
  {
    const ull* s2 = (const ull*)hhL[(NCH - 1) & 1];
    ull* d2 = (ull*)(hs + hsbase + (size_t)(NCH - 1) * TC * 16);
    for (int i = tid; i < TC * 8; i += 512)
      __hip_atomic_store(&d2[i], s2[i], __ATOMIC_RELAXED,
                         __HIP_MEMORY_SCOPE_AGENT);
  }
  __syncthreads();                              // drains vmcnt: epi + ch30 flush
  if (tid == 511) {
    __hip_atomic_store(&flags[b], NCH, __ATOMIC_RELAXED,
                       __HIP_MEMORY_SCOPE_AGENT);
  }
  if (tid < 16) hfin[b * 16 + tid] = h;
}

// ---------------------------------------------------------------- launcher
extern "C" void kernel_launch(void* const* d_in, const int* in_sizes, int n_in,
                              void* d_out, int out_size, void* d_ws, size_t ws_size,
                              hipStream_t stream) {
  const float* x       = (const float*)d_in[0];
  const float* h0      = (const float*)d_in[1];
  const float* mask    = (const float*)d_in[2];
  const float* A_diag  = (const float*)d_in[3];
  const float* W_delta = (const float*)d_in[4];
  const float* W_B     = (const float*)d_in[5];
  const float* W_C     = (const float*)d_in[6];
  const float* W_out   = (const float*)d_in[7];
  const float* Dd      = (const float*)d_in[8];
  const float* W_gate  = (const float*)d_in[9];
  const float* b_gate  = (const float*)d_in[10];
  const float* ln_w    = (const float*)d_in[11];
  const float* ln_b    = (const float*)d_in[12];

  char* ws = (char*)d_ws;
  unsigned short* Xb   = (unsigned short*)(ws);               // 64 MB
  unsigned short* Gb   = (unsigned short*)(ws + 67108864);    // 64 MB
  unsigned short* Wgb  = (unsigned short*)(ws + 134217728);   // 2 MB
  unsigned short* Wcat = (unsigned short*)(ws + 136314880);   // 96 KB of 128 KB slot
  int* sync_arr = (int*)(ws + 136413184);                     // 1056 B in pad gap
  float* UVb = (float*)(ws + 136445952);                      // 4 MB {u,v}
  float* hsb = (float*)(ws + 142737408);                      // 2 MB (end 144834560, same as verified)

  float* y    = (float*)d_out;
  float* hfin = y + 33554432;

  hipLaunchKernelGGL(k_convert, dim3(33840), dim3(256), 0, stream,
                     x, W_gate, W_delta, W_B, W_C, Xb, Wgb, Wcat, sync_arr);
  hipLaunchKernelGGL(k_gemm_gate, dim3(256, 8), dim3(256), 0, stream, Xb, Wgb, Gb);
  hipLaunchKernelGGL(k_fused, dim3(8 + NWRK), dim3(512), 0, stream,
                     UVb, mask, h0, hsb, hfin, x, W_out, Dd, y, sync_arr,
                     Gb, b_gate, ln_w, ln_b, Wcat, A_diag);
}

// Round 6
// 497.855 us; speedup vs baseline: 2.7087x; 2.7087x over previous
//
#include <hip/hip_runtime.h>
#include <hip/hip_bf16.h>
#include <cstdint>

// SimplifiedMambaSSM on MI355X (gfx950)
// B=8, T=4096, D_MODEL=1024, D_STATE=16. Rows M = B*T = 32768.
//
// Pipeline (R6: reverted R5's producer-consumer proj fold -- its per-row
// wave-parallel dots re-read G/x 4x and thrashed Wcat through L2, FETCH
// 2.3GB, kernel became pure-BW-bound at 1083us. Instead: K3+K4 fused as a
// plain tiled kernel with on-the-fly xg):
//  K1 convert : x, W_gate, [W_delta;W_B;W_C] -> bf16 workspace copies
//  K2 gemm    : G = Xb @ Wgb^T  (bf16 MFMA, 128x128 tiles, XCD-swizzled)
//  K34 lnproj : per 64-row block: phase1 = LN stats (coalesced G reads,
//               wave per 16 rows); phase2 = old K4 k-loop with the A-tile
//               (xg bf16) computed on the fly from G,x,stats (kills the
//               64MB XG write + 64MB XG read); epilogue folds softplus/
//               exp(A_diag)/2log2e -> {u,v}; Ct flat; zeroes flags.
//  K5 scan+out: R4-verified FUSED kernel (130us):
//               blocks 0..7 scan (consumer wave setprio(3), agent
//               write-through hs flush, relaxed flag publish);
//               blocks 8..519 output GEMM, 2 rows/iter, bounded spins.
//
#define M_TOK   32768
#define LNEPS   1e-5f
#define TWO_LOG2E 2.8853900817779268f   // 2/ln(2)

typedef float  f32x4 __attribute__((ext_vector_type(4)));
typedef short  s16x8 __attribute__((ext_vector_type(8)));
typedef unsigned long long ull;

__device__ __forceinline__ unsigned short f2b(float v) {
  return __builtin_bit_cast(unsigned short, __float2bfloat16(v));
}
__device__ __forceinline__ float b2f(unsigned short u) {
  return __bfloat162float(__builtin_bit_cast(__hip_bfloat16, u));
}
__device__ __forceinline__ float red64(float v) {
#pragma unroll
  for (int off = 32; off >= 1; off >>= 1) v += __shfl_xor(v, off, 64);
  return v;
}

// async global->LDS, 16B per lane. LDS dest is wave-uniform base + lane*16.
__device__ __forceinline__ void async_cp16(const void* g, void* l) {
  using gp = const __attribute__((address_space(1))) char*;
  using lp = __attribute__((address_space(3))) char*;
  __builtin_amdgcn_global_load_lds((gp)(uint64_t)g,
                                   (lp)(uint32_t)(uint64_t)l, 16, 0, 0);
}

// ---------------------------------------------------------------- K1 convert
__global__ __launch_bounds__(256) void k_convert(
    const float* __restrict__ x, const float* __restrict__ wg,
    const float* __restrict__ wd, const float* __restrict__ wb,
    const float* __restrict__ wc,
    unsigned short* __restrict__ Xb, unsigned short* __restrict__ Wgb,
    unsigned short* __restrict__ Wcat) {
  int i = blockIdx.x * 256 + threadIdx.x;   // one float4 per thread
  const float* src;
  unsigned short* dst;
  if (i < 8388608) {                  // x: 33554432 floats
    src = x + (size_t)i * 4; dst = Xb + (size_t)i * 4;
  } else if (i < 8650752) {           // W_gate: 1048576 floats
    int j = i - 8388608;
    src = wg + (size_t)j * 4; dst = Wgb + (size_t)j * 4;
  } else {                            // Wcat = [W_delta; W_B; W_C], 49152 floats
    int j = i - 8650752;
    int e = j * 4;
    if (e < 16384)       src = wd + e;
    else if (e < 32768)  src = wb + (e - 16384);
    else                 src = wc + (e - 32768);
    dst = Wcat + e;
  }
  float4 v = *(const float4*)src;
  ushort4 o;
  o.x = f2b(v.x); o.y = f2b(v.y); o.z = f2b(v.z); o.w = f2b(v.w);
  *(ushort4*)dst = o;
}

// ------------------------------------------------------------- K2 gate GEMM
// G[m][n] = sum_k Xb[m][k] * Wgb[n][k]   (NT, both K-contiguous)
// 128x128 block tile, 4 waves in 2x2, each wave 64x64 = 4x4 MFMA 16x16x32.
__global__ __launch_bounds__(256, 2) void k_gemm_gate(
    const unsigned short* __restrict__ A,   // [32768][1024] bf16
    const unsigned short* __restrict__ Bm,  // [1024][1024] bf16 (W_gate rows)
    unsigned short* __restrict__ C) {       // [32768][1024] bf16
  __shared__ unsigned short As[128 * 32];   // 8 KB
  __shared__ unsigned short Bs[128 * 32];   // 8 KB
  const int tid  = threadIdx.x;
  const int wave = tid >> 6, lane = tid & 63;
  const int wr = wave >> 1, wc = wave & 1;
  const int lrow = lane & 15, lq = lane >> 4;
  // XCD-aware swizzle: each XCD owns 32 M-panels x all 8 N-tiles.
  const int lin  = blockIdx.y * gridDim.x + blockIdx.x;     // 0..2047
  const int unit = (lin & 7) * 256 + (lin >> 3);
  const int m0 = (unit >> 3) * 128;
  const int n0 = (unit & 7) * 128;
  const int crow  = tid >> 2;               // staging chunk row (rep 0)
  const int ccol  = (tid & 3) * 8;          // staging chunk col (elems)

  f32x4 acc[4][4];
#pragma unroll
  for (int i = 0; i < 4; i++)
#pragma unroll
    for (int j = 0; j < 4; j++) acc[i][j] = (f32x4){0.f, 0.f, 0.f, 0.f};

  for (int k0 = 0; k0 < 1024; k0 += 32) {
    async_cp16(A + (size_t)(m0 + crow) * 1024 + k0 + ccol,
               (void*)(As + (wave * 64) * 8));
    async_cp16(A + (size_t)(m0 + crow + 64) * 1024 + k0 + ccol,
               (void*)(As + (256 + wave * 64) * 8));
    async_cp16(Bm + (size_t)(n0 + crow) * 1024 + k0 + ccol,
               (void*)(Bs + (wave * 64) * 8));
    async_cp16(Bm + (size_t)(n0 + crow + 64) * 1024 + k0 + ccol,
               (void*)(Bs + (256 + wave * 64) * 8));
    __syncthreads();   // drains vmcnt (global_load_lds) before LDS reads

    s16x8 af[4], bfr[4];
#pragma unroll
    for (int i = 0; i < 4; i++)
      af[i] = *(const s16x8*)(As + (wr * 64 + i * 16 + lrow) * 32 + lq * 8);
#pragma unroll
    for (int j = 0; j < 4; j++)
      bfr[j] = *(const s16x8*)(Bs + (wc * 64 + j * 16 + lrow) * 32 + lq * 8);
#pragma unroll
    for (int i = 0; i < 4; i++)
#pragma unroll
      for (int j = 0; j < 4; j++)
        acc[i][j] = __builtin_amdgcn_mfma_f32_16x16x32_bf16(
            af[i], bfr[j], acc[i][j], 0, 0, 0);
    __syncthreads();
  }

  // C/D layout: col = lane&15, row = (lane>>4)*4 + reg
#pragma unroll
  for (int i = 0; i < 4; i++)
#pragma unroll
    for (int j = 0; j < 4; j++)
#pragma unroll
      for (int r = 0; r < 4; r++) {
        int row = m0 + wr * 64 + i * 16 + lq * 4 + r;
        int col = n0 + wc * 64 + j * 16 + lrow;
        C[(size_t)row * 1024 + col] = f2b(acc[i][j][r]);
      }
}

// ------------------------------------------------------- K34 LN+gate+proj
// One block = 64 rows. Phase 1: LN stats per row (coalesced full-row G
// reads, wave w handles rows 16w..16w+15, red64). Phase 2: K4's k-loop,
// A-tile (xg bf16) computed on the fly: xg = sigmoid(LN(G+bg))*x, rounded
// to bf16 exactly like the old K3->XG->K4 path (same numerics).
// Epilogue: {u = A2+B2, v = -2*A2} r-domain pairs + Ct flat; zeroes flags.
__global__ __launch_bounds__(256) void k_lnproj(
    const unsigned short* __restrict__ G,   // [32768][1024] bf16
    const float* __restrict__ x,
    const float* __restrict__ bgp, const float* __restrict__ lnw,
    const float* __restrict__ lnb,
    const unsigned short* __restrict__ Wcat,
    const float* __restrict__ A_diag,
    float* __restrict__ UV, float* __restrict__ Ct, int* __restrict__ flags) {
  __shared__ unsigned short As[64 * 32];   // 4 KB (xg tile bf16)
  __shared__ unsigned short Bs[48 * 32];   // 3 KB (Wcat tile)
  __shared__ float muL[64], rsL[64];       // 512 B
  const int tid  = threadIdx.x;
  const int wave = tid >> 6, lane = tid & 63;
  const int lrow = lane & 15, lq = lane >> 4;
  const int r0 = blockIdx.x * 64;
  const int crow = tid >> 2, ccol = (tid & 3) * 8;

  if (blockIdx.x == 0 && tid < 8)
    __hip_atomic_store(&flags[tid], 0, __ATOMIC_RELAXED,
                       __HIP_MEMORY_SCOPE_AGENT);   // write-through zeroing

  // ---- phase 1: LN stats. Lane covers cols [lane*8, +8) and [512+lane*8, +8)
  {
    float bga[8], bgb[8];
    *(float4*)&bga[0] = *(const float4*)(bgp + lane * 8);
    *(float4*)&bga[4] = *(const float4*)(bgp + lane * 8 + 4);
    *(float4*)&bgb[0] = *(const float4*)(bgp + 512 + lane * 8);
    *(float4*)&bgb[4] = *(const float4*)(bgp + 512 + lane * 8 + 4);
    for (int rr = 0; rr < 16; ++rr) {
      const int row = wave * 16 + rr;
      const unsigned short* gp = G + (size_t)(r0 + row) * 1024;
      s16x8 ga = *(const s16x8*)(gp + lane * 8);
      s16x8 gb = *(const s16x8*)(gp + 512 + lane * 8);
      float s = 0.f, ss = 0.f;
#pragma unroll
      for (int i = 0; i < 8; i++) {
        float va = b2f((unsigned short)ga[i]) + bga[i];
        float vb = b2f((unsigned short)gb[i]) + bgb[i];
        s  += va + vb;
        ss += va * va + vb * vb;
      }
      s = red64(s); ss = red64(ss);
      if (lane == 0) {
        float mu  = s * (1.0f / 1024.0f);
        float var = ss * (1.0f / 1024.0f) - mu * mu;
        muL[row] = mu;
        rsL[row] = rsqrtf(var + LNEPS);
      }
    }
  }
  __syncthreads();
  const float mu = muL[crow];
  const float rs = rsL[crow];

  f32x4 acc[3];
#pragma unroll
  for (int j = 0; j < 3; j++) acc[j] = (f32x4){0.f, 0.f, 0.f, 0.f};

  for (int k0 = 0; k0 < 1024; k0 += 32) {
    // register-stage G/x/params/Wcat (G re-read hits L2: 128KB/block hot)
    s16x8 gv = *(const s16x8*)(G + (size_t)(r0 + crow) * 1024 + k0 + ccol);
    float xs[8], bgs[8], lws[8], lbs[8];
    *(float4*)&xs[0]  = *(const float4*)(x   + (size_t)(r0 + crow) * 1024 + k0 + ccol);
    *(float4*)&xs[4]  = *(const float4*)(x   + (size_t)(r0 + crow) * 1024 + k0 + ccol + 4);
    *(float4*)&bgs[0] = *(const float4*)(bgp + k0 + ccol);
    *(float4*)&bgs[4] = *(const float4*)(bgp + k0 + ccol + 4);
    *(float4*)&lws[0] = *(const float4*)(lnw + k0 + ccol);
    *(float4*)&lws[4] = *(const float4*)(lnw + k0 + ccol + 4);
    *(float4*)&lbs[0] = *(const float4*)(lnb + k0 + ccol);
    *(float4*)&lbs[4] = *(const float4*)(lnb + k0 + ccol + 4);
    uint4 bv;
    if (tid < 192) bv = *(const uint4*)(Wcat + (size_t)crow * 1024 + k0 + ccol);
    __syncthreads();                       // prev iter done reading LDS
    // xg = sigmoid((v-mu)*rs*lnw + lnb) * x, rounded to bf16 (as old K3)
    s16x8 ov;
#pragma unroll
    for (int i = 0; i < 8; i++) {
      float v = b2f((unsigned short)gv[i]) + bgs[i];
      float u = (v - mu) * rs * lws[i] + lbs[i];
      float g = 1.0f / (1.0f + __expf(-u));
      ov[i] = (short)f2b(g * xs[i]);
    }
    *(s16x8*)(As + crow * 32 + ccol) = ov;
    if (tid < 192) *(uint4*)(Bs + crow * 32 + ccol) = bv;
    __syncthreads();
    s16x8 af = *(const s16x8*)(As + (wave * 16 + lrow) * 32 + lq * 8);
#pragma unroll
    for (int j = 0; j < 3; j++) {
      s16x8 bf8 = *(const s16x8*)(Bs + (j * 16 + lrow) * 32 + lq * 8);
      acc[j] = __builtin_amdgcn_mfma_f32_16x16x32_bf16(af, bf8, acc[j], 0, 0, 0);
    }
  }

  float ad = A_diag[lrow];
#pragma unroll
  for (int r = 0; r < 4; r++) {
    int row = r0 + wave * 16 + lq * 4 + r;
    float z  = acc[0][r];
    float sp = fmaxf(z, 0.0f) + log1pf(__expf(-fabsf(z)));  // softplus
    float A2 = __expf(sp * ad) * TWO_LOG2E;                  // A_bar scaled
    float B2 = acc[1][r] * TWO_LOG2E;
    float2 o;
    o.x = A2 + B2;          // u
    o.y = -2.0f * A2;       // v
    *(float2*)(UV + (size_t)row * 32 + lrow * 2) = o;
    Ct[(size_t)row * 16 + lrow] = acc[2][r];
  }
}

// --------------------------------------------------------- K5 scan + output
#define TC 128                // steps per chunk
#define NCH (4096 / TC)       // 32 chunks
#define NOUT 512              // output blocks; 1024 rows/chunk = 2 per block

__device__ __forceinline__ void load16(float2 (&P)[16], const float* uvb,
                                       int j, int lane) {
#pragma unroll
  for (int i = 0; i < 16; ++i)
    P[i] = *(const float2*)(uvb + ((j * 16 + i) * 16 + lane) * 2);
}
__device__ __forceinline__ void fast16(float2 (&P)[16], float& r, float& h,
                                       float* hhb, int j, int lane) {
#pragma unroll
  for (int i = 0; i < 16; ++i) {
    float w = fmaf(P[i].y, r, P[i].x);
    float e = __builtin_amdgcn_exp2f(w);
    r = __builtin_amdgcn_rcpf(e + 1.0f);
    h = fmaf(-2.0f, r, 1.0f);
    hhb[(j * 16 + i) * 16 + lane] = h;
  }
}
__device__ __forceinline__ void slow16(float2 (&P)[16], float& h,
                                       const float* mb, float* hhb,
                                       int j, int lane) {
#pragma unroll
  for (int i = 0; i < 16; ++i) {
    float v  = P[i].y, u = P[i].x;
    float A2 = -0.5f * v;
    float B2 = fmaf(0.5f, v, u);
    float w  = fmaf(A2, h, B2);
    float e  = __builtin_amdgcn_exp2f(w);
    float rr = __builtin_amdgcn_rcpf(e + 1.0f);
    float th = fmaf(-2.0f, rr, 1.0f);
    float m  = mb[j * 16 + i];
    h = fmaf(m, th - h, h);
    hhb[(j * 16 + i) * 16 + lane] = h;
  }
}

__global__ __launch_bounds__(512, 6) void k_scan_out(
    const float* __restrict__ UV, const float* __restrict__ mask,
    const float* __restrict__ h0, float* __restrict__ hs,
    float* __restrict__ hfin,
    const float* __restrict__ Ct, const float* __restrict__ x,
    const float* __restrict__ Wout, const float* __restrict__ Dd,
    float* __restrict__ y, int* __restrict__ flags) {
  __shared__ float uvL[2][TC * 32];    // 2 x 16 KB
  __shared__ float hhL[2][TC * 16];    // 2 x 8 KB
  __shared__ float mskL[2][TC];        // 2 x 512 B

  const int tid = threadIdx.x;

  if (blockIdx.x >= 8) {
    // ============================ OUTPUT ROLE ============================
    const int o    = blockIdx.x - 8;          // 0..511
    const int wv   = tid >> 6;
    const int lane = tid & 63;
    const int d0   = wv * 128 + lane * 2;
    const int b0   = o >> 7;                  // 0..3
    const int b1   = b0 + 4;                  // 4..7
    const int j0   = o & 127;

    float wa[16], wb[16];
#pragma unroll
    for (int q = 0; q < 4; q++) {
      *(float4*)&wa[q * 4] = *(const float4*)(Wout + (size_t)d0 * 16 + q * 4);
      *(float4*)&wb[q * 4] = *(const float4*)(Wout + (size_t)(d0 + 1) * 16 + q * 4);
    }
    float2 D2 = *(const float2*)(Dd + d0);

    for (int c = 0; c < NCH; ++c) {
      size_t r0 = (size_t)b0 * 4096 + (size_t)c * TC + j0;
      size_t r1 = (size_t)b1 * 4096 + (size_t)c * TC + j0;
      int spins = 0;
      for (;;) {
        int f = 0;
        if (lane == 0) {
          int fa = __hip_atomic_load(&flags[b0], __ATOMIC_RELAXED,
                                     __HIP_MEMORY_SCOPE_AGENT);
          int fb = __hip_atomic_load(&flags[b1], __ATOMIC_RELAXED,
                                     __HIP_MEMORY_SCOPE_AGENT);
          f = (fa < fb) ? fa : fb;
        }
        f = __shfl(f, 0);
        if (f > c || spins > (1 << 18)) break;
        ++spins;
        __builtin_amdgcn_s_sleep(32);
      }
      float cv0 = Ct[r0 * 16 + (lane & 15)];
      float cv1 = Ct[r1 * 16 + (lane & 15)];
      float hv0 = __hip_atomic_load(&hs[r0 * 16 + (lane & 15)],
                                    __ATOMIC_RELAXED, __HIP_MEMORY_SCOPE_AGENT);
      float hv1 = __hip_atomic_load(&hs[r1 * 16 + (lane & 15)],
                                    __ATOMIC_RELAXED, __HIP_MEMORY_SCOPE_AGENT);
      float2 x20 = *(const float2*)(x + r0 * 1024 + d0);
      float2 x21 = *(const float2*)(x + r1 * 1024 + d0);
      float sv0 = cv0 * hv0;
      float sv1 = cv1 * hv1;
      float a0x = D2.x * x20.x, a0y = D2.y * x20.y;
      float a1x = D2.x * x21.x, a1y = D2.y * x21.y;
#pragma unroll
      for (int s = 0; s < 16; s++) {
        float s0 = __shfl(sv0, s);
        float s1 = __shfl(sv1, s);
        a0x = fmaf(wa[s], s0, a0x);
        a0y = fmaf(wb[s], s0, a0y);
        a1x = fmaf(wa[s], s1, a1x);
        a1y = fmaf(wb[s], s1, a1y);
      }
      float2 o0; o0.x = a0x; o0.y = a0y;
      float2 o1; o1.x = a1x; o1.y = a1y;
      *(float2*)(y + r0 * 1024 + d0) = o0;
      *(float2*)(y + r1 * 1024 + d0) = o1;
    }
    return;
  }

  // ============================== SCAN ROLE ==============================
  const int b   = blockIdx.x;
  const float* pm = mask + (size_t)b * 4096;
  const size_t uvbase = (size_t)b * 4096 * 32;   // floats
  const size_t hsbase = (size_t)b * 4096 * 16;   // floats

  if (tid < 64) __builtin_amdgcn_s_setprio(3);   // critical recurrence wave

  float h = 0.f, r = 0.f;
  if (tid < 16) {
    h = h0[b * 16 + tid];
    r = 0.5f - 0.5f * h;        // invariant r = (1-h)/2
  }

  // ---- priming: load chunk 0 (UV + mask)
  if (tid >= 64) {
    int pt = tid - 64;                          // 0..447
    const uint4* src = (const uint4*)(UV + uvbase);
    for (int i = pt; i < TC * 8; i += 448) ((uint4*)uvL[0])[i] = src[i];
    if (tid < 128) {
      int l = tid - 64;
      mskL[0][l]      = pm[l];
      mskL[0][l + 64] = pm[l + 64];
    }
  }
  __syncthreads();

  for (int c = 0; c < NCH; ++c) {
    // publish chunks 0..c-2: their agent write-through stores were drained
    // by iteration c-1's pre-barrier vmcnt(0); relaxed store suffices.
    if (c >= 2 && tid == 511) {
      __hip_atomic_store(&flags[b], c - 1, __ATOMIC_RELAXED,
                         __HIP_MEMORY_SCOPE_AGENT);
    }
    const int p = c & 1;
    if (tid < 64) {
      // ---------------- consumer wave
      const int lane = tid;
      float mv0 = mskL[p][2 * lane], mv1 = mskL[p][2 * lane + 1];
      bool on = (mv0 == 1.0f) && (mv1 == 1.0f);
      bool allones = (__ballot(on) == 0xFFFFFFFFFFFFFFFFull);
      if (lane < 16) {
        const float* uvb = uvL[p];
        float* hhb = hhL[p];
        float2 Pa[16], Pb[16];
        load16(Pa, uvb, 0, lane);
        if (allones) {
#pragma unroll
          for (int j = 0; j < 8; j += 2) {
            load16(Pb, uvb, j + 1, lane);
            fast16(Pa, r, h, hhb, j, lane);
            if (j + 2 < 8) load16(Pa, uvb, j + 2, lane);
            fast16(Pb, r, h, hhb, j + 1, lane);
          }
        } else {
#pragma unroll
          for (int j = 0; j < 8; j += 2) {
            load16(Pb, uvb, j + 1, lane);
            slow16(Pa, h, mskL[p], hhb, j, lane);
            if (j + 2 < 8) load16(Pa, uvb, j + 2, lane);
            slow16(Pb, h, mskL[p], hhb, j + 1, lane);
          }
          r = 0.5f - 0.5f * h;
        }
      }
    } else {
      // ---------------- producer waves 1..7
      int pt = tid - 64;                        // 0..447
      if (c + 1 < NCH) {
        const uint4* src =
            (const uint4*)(UV + uvbase + (size_t)(c + 1) * TC * 32);
        uint4* dst = (uint4*)uvL[(c + 1) & 1];
        for (int i = pt; i < TC * 8; i += 448) dst[i] = src[i];
        if (tid < 128) {
          int l = tid - 64;
          mskL[(c + 1) & 1][l]      = pm[(c + 1) * TC + l];
          mskL[(c + 1) & 1][l + 64] = pm[(c + 1) * TC + l + 64];
        }
      }
      if (c > 0) {
        // flush chunk c-1 h-history: agent write-through 8B stores
        const ull* s2 = (const ull*)hhL[(c - 1) & 1];
        ull* d2 = (ull*)(hs + hsbase + (size_t)(c - 1) * TC * 16);
        for (int i = pt; i < TC * 8; i += 448)
          __hip_atomic_store(&d2[i], s2[i], __ATOMIC_RELAXED,
                             __HIP_MEMORY_SCOPE_AGENT);
      }
    }
    __syncthreads();
  }

  // ---- epilogue: store last chunk's h-history
  {
    const ull* s2 = (const ull*)hhL[(NCH - 1) & 1];
    ull* d2 = (ull*)(hs + hsbase + (size_t)(NCH - 1) * TC * 16);
    for (int i = tid; i < TC * 8; i += 512)
      __hip_atomic_store(&d2[i], s2[i], __ATOMIC_RELAXED,
                         __HIP_MEMORY_SCOPE_AGENT);
  }
  __syncthreads();                              // drains vmcnt: epi + ch30 flush
  if (tid == 511) {
    __hip_atomic_store(&flags[b], NCH, __ATOMIC_RELAXED,
                       __HIP_MEMORY_SCOPE_AGENT);
  }
  if (tid < 16) hfin[b * 16 + tid] = h;
}

// ---------------------------------------------------------------- launcher
extern "C" void kernel_launch(void* const* d_in, const int* in_sizes, int n_in,
                              void* d_out, int out_size, void* d_ws, size_t ws_size,
                              hipStream_t stream) {
  const float* x       = (const float*)d_in[0];
  const float* h0      = (const float*)d_in[1];
  const float* mask    = (const float*)d_in[2];
  const float* A_diag  = (const float*)d_in[3];
  const float* W_delta = (const float*)d_in[4];
  const float* W_B     = (const float*)d_in[5];
  const float* W_C     = (const float*)d_in[6];
  const float* W_out   = (const float*)d_in[7];
  const float* Dd      = (const float*)d_in[8];
  const float* W_gate  = (const float*)d_in[9];
  const float* b_gate  = (const float*)d_in[10];
  const float* ln_w    = (const float*)d_in[11];
  const float* ln_b    = (const float*)d_in[12];

  char* ws = (char*)d_ws;
  unsigned short* Xb   = (unsigned short*)(ws);               // 64 MB
  unsigned short* Gb   = (unsigned short*)(ws + 67108864);    // 64 MB
  unsigned short* Wgb  = (unsigned short*)(ws + 134217728);   // 2 MB
  unsigned short* Wcat = (unsigned short*)(ws + 136314880);   // 96 KB of 128 KB slot
  int* flags = (int*)(ws + 136413184);                        // 32 B, in pad gap
  float* UVb = (float*)(ws + 136445952);                      // 4 MB {u,v}
  float* Ctb = (float*)(ws + 140640256);                      // 2 MB
  float* hsb = (float*)(ws + 142737408);                      // 2 MB (end 144834560, verified footprint)

  float* y    = (float*)d_out;
  float* hfin = y + 33554432;

  hipLaunchKernelGGL(k_convert, dim3(33840), dim3(256), 0, stream,
                     x, W_gate, W_delta, W_B, W_C, Xb, Wgb, Wcat);
  hipLaunchKernelGGL(k_gemm_gate, dim3(256, 8), dim3(256), 0, stream, Xb, Wgb, Gb);
  hipLaunchKernelGGL(k_lnproj, dim3(512), dim3(256), 0, stream,
                     Gb, x, b_gate, ln_w, ln_b, Wcat, A_diag, UVb, Ctb, flags);
  hipLaunchKernelGGL(k_scan_out, dim3(8 + NOUT), dim3(512), 0, stream,
                     UVb, mask, h0, hsb, hfin, Ctb, x, W_out, Dd, y, flags);
}